// Round 1
// baseline (439.440 us; speedup 1.0000x reference)
//
#include <hip/hip_runtime.h>

#define NBINS  10
#define NCLS   80
#define NSLOTS (NCLS * NBINS)   // 800

// ---------------------------------------------------------------------------
// Kernel 1: per-(class,bin) accumulation of {count, sum_p, sum_correct}
// via per-block LDS histograms flushed with global atomics.
// ---------------------------------------------------------------------------
__global__ void __launch_bounds__(256)
mce_accum(const float4* __restrict__ probas,
          const int*    __restrict__ labels,
          unsigned int* __restrict__ g_cnt,
          float*        __restrict__ g_sum,
          unsigned int* __restrict__ g_acc,
          long long nvec) {
    __shared__ unsigned int s_cnt[NSLOTS];
    __shared__ float        s_sum[NSLOTS];
    __shared__ unsigned int s_acc[NSLOTS];

    for (int i = threadIdx.x; i < NSLOTS; i += blockDim.x) {
        s_cnt[i] = 0u; s_sum[i] = 0.0f; s_acc[i] = 0u;
    }
    __syncthreads();

    const int VPR = NCLS / 4;  // float4 vectors per row = 20
    const long long stride = (long long)gridDim.x * blockDim.x;

    for (long long v = (long long)blockIdx.x * blockDim.x + threadIdx.x;
         v < nvec; v += stride) {
        float4 p4 = probas[v];
        int row   = (int)(v / VPR);
        int cbase = ((int)(v % VPR)) * 4;
        int lab   = labels[row];  // L1-broadcast across the 20 vectors of a row

        float pv[4] = {p4.x, p4.y, p4.z, p4.w};
        #pragma unroll
        for (int j = 0; j < 4; ++j) {
            float p = pv[j];
            // bin = (#edges strictly < p) - 1, edges e[k] = k*0.1f (fp32 linspace)
            int b = (int)(p * 10.0f);
            if (b > 9) b = 9;
            float eb = (float)b * 0.1f;
            if (!(eb < p)) {
                b -= 1;                    // p <= e[b]  (also routes p==0 -> -1)
            } else {
                float eb1 = (float)(b + 1) * 0.1f;
                if (eb1 < p) b += 1;       // p > e[b+1]
            }
            if (b >= 0) {
                int cls  = cbase + j;
                int slot = cls * NBINS + b;
                atomicAdd(&s_cnt[slot], 1u);
                atomicAdd(&s_sum[slot], p);
                if (lab == cls) atomicAdd(&s_acc[slot], 1u);
            }
        }
    }
    __syncthreads();

    for (int i = threadIdx.x; i < NSLOTS; i += blockDim.x) {
        unsigned int c = s_cnt[i];
        if (c)           atomicAdd(&g_cnt[i], c);
        float s = s_sum[i];
        if (s != 0.0f)   atomicAdd(&g_sum[i], s);
        unsigned int a = s_acc[i];
        if (a)           atomicAdd(&g_acc[i], a);
    }
}

// ---------------------------------------------------------------------------
// Kernel 2: finalize — per-class weighted squared calibration error,
// mean over classes, sqrt. One block, 128 threads (80 active).
// ---------------------------------------------------------------------------
__global__ void __launch_bounds__(128)
mce_finalize(const unsigned int* __restrict__ g_cnt,
             const float*        __restrict__ g_sum,
             const unsigned int* __restrict__ g_acc,
             float* __restrict__ out) {
    __shared__ float s_ce[128];
    int c = threadIdx.x;
    float ce = 0.0f;
    if (c < NCLS) {
        float total = 0.0f;
        for (int b = 0; b < NBINS; ++b)
            total += (float)g_cnt[c * NBINS + b];
        for (int b = 0; b < NBINS; ++b) {
            unsigned int n = g_cnt[c * NBINS + b];
            if (n > 0u) {
                float fn   = (float)n;
                float conf = g_sum[c * NBINS + b] / fn;
                float acc  = (float)g_acc[c * NBINS + b] / fn;
                float d    = conf - acc;
                ce += (fn / total) * d * d;
            }
        }
    }
    s_ce[c] = ce;
    __syncthreads();
    for (int off = 64; off > 0; off >>= 1) {
        if (c < off) s_ce[c] += s_ce[c + off];
        __syncthreads();
    }
    if (c == 0) out[0] = sqrtf(s_ce[0] / (float)NCLS);
}

extern "C" void kernel_launch(void* const* d_in, const int* in_sizes, int n_in,
                              void* d_out, int out_size, void* d_ws, size_t ws_size,
                              hipStream_t stream) {
    const float4* probas = (const float4*)d_in[0];
    const int*    labels = (const int*)d_in[1];

    long long total_elems = (long long)in_sizes[0];   // N * C = 80,000,000
    long long nvec        = total_elems / 4;          // 20,000,000

    unsigned int* g_cnt = (unsigned int*)d_ws;
    float*        g_sum = (float*)((char*)d_ws + NSLOTS * sizeof(unsigned int));
    unsigned int* g_acc = (unsigned int*)((char*)d_ws + NSLOTS * (sizeof(unsigned int) + sizeof(float)));

    hipMemsetAsync(d_ws, 0, NSLOTS * 3 * sizeof(unsigned int), stream);

    const int threads = 256;
    const int blocks  = 2048;   // 256 CU x 8 blocks, grid-stride
    mce_accum<<<blocks, threads, 0, stream>>>(probas, labels, g_cnt, g_sum, g_acc, nvec);
    mce_finalize<<<1, 128, 0, stream>>>(g_cnt, g_sum, g_acc, (float*)d_out);
}

// Round 2
// 91.141 us; speedup vs baseline: 4.8216x; 4.8216x over previous
//
#include <hip/hip_runtime.h>

#define NBINS  10
#define NCLS   80
#define NSLOTS (NCLS * NBINS)   // 800
#define QSCALE 262144.0f        // 2^18 fixed-point scale for sum(p)

// ---------------------------------------------------------------------------
// Kernel 1: per-(class,bin) accumulation. One packed u64 LDS atomic per
// element: bits 0..39 = quantized sum_p, 40..51 = count, 52..63 = correct.
// ---------------------------------------------------------------------------
__global__ void __launch_bounds__(256)
mce_accum(const float4* __restrict__ probas,
          const int*    __restrict__ labels,
          unsigned int*       __restrict__ g_cnt,
          unsigned int*       __restrict__ g_acc,
          unsigned long long* __restrict__ g_sum,
          unsigned int nvec) {
    __shared__ unsigned long long s_pack[NSLOTS];

    for (int i = threadIdx.x; i < NSLOTS; i += 256) s_pack[i] = 0ull;
    __syncthreads();

    const unsigned int stride = gridDim.x * 256u * 2u;

    for (unsigned int v = (blockIdx.x * 256u + threadIdx.x) * 2u;
         v < nvec; v += stride) {
        float4 pa = probas[v];
        float4 pb = probas[v + 1];           // v even, nvec even -> in range
        unsigned int row = v / 20u;          // 32-bit magic div
        int cbase = (int)(v - row * 20u) * 4;
        int lab   = labels[row];

        float pv[8] = {pa.x, pa.y, pa.z, pa.w, pb.x, pb.y, pb.z, pb.w};
        #pragma unroll
        for (int j = 0; j < 8; ++j) {
            float p = pv[j];
            // bin = (#edges < p) - 1, edges ~ k*0.1f; p==0 -> -1 (dropped)
            int b = (int)(p * 10.0f);
            if (b > 9) b = 9;
            float eb = (float)b * 0.1f;
            if (!(eb < p)) {
                b -= 1;
            } else {
                float eb1 = (float)(b + 1) * 0.1f;
                if (eb1 < p) b += 1;
            }
            if (b >= 0) {
                int cls  = cbase + j;
                int slot = cls * NBINS + b;
                unsigned long long q = (unsigned long long)(unsigned int)(p * QSCALE + 0.5f);
                unsigned long long inc = q | (1ull << 40)
                                       | ((lab == cls) ? (1ull << 52) : 0ull);
                atomicAdd(&s_pack[slot], inc);   // native ds_add_u64
            }
        }
    }
    __syncthreads();

    for (int i = threadIdx.x; i < NSLOTS; i += 256) {
        unsigned long long v = s_pack[i];
        if (v) {
            unsigned int cnt = (unsigned int)((v >> 40) & 0xFFFull);
            unsigned int acc = (unsigned int)(v >> 52);
            unsigned long long q = v & 0xFFFFFFFFFFull;
            atomicAdd(&g_cnt[i], cnt);
            if (acc) atomicAdd(&g_acc[i], acc);
            atomicAdd(&g_sum[i], q);
        }
    }
}

// ---------------------------------------------------------------------------
// Kernel 2: finalize in double precision. One block, 128 threads (80 active).
// ---------------------------------------------------------------------------
__global__ void __launch_bounds__(128)
mce_finalize(const unsigned int*       __restrict__ g_cnt,
             const unsigned int*       __restrict__ g_acc,
             const unsigned long long* __restrict__ g_sum,
             float* __restrict__ out) {
    __shared__ double s_ce[128];
    int c = threadIdx.x;
    double ce = 0.0;
    if (c < NCLS) {
        double total = 0.0;
        for (int b = 0; b < NBINS; ++b)
            total += (double)g_cnt[c * NBINS + b];
        for (int b = 0; b < NBINS; ++b) {
            unsigned int n = g_cnt[c * NBINS + b];
            if (n > 0u) {
                double fn   = (double)n;
                double conf = ((double)g_sum[c * NBINS + b] * (1.0 / 262144.0)) / fn;
                double acc  = (double)g_acc[c * NBINS + b] / fn;
                double d    = conf - acc;
                ce += (fn / total) * d * d;
            }
        }
    }
    s_ce[c] = ce;
    __syncthreads();
    for (int off = 64; off > 0; off >>= 1) {
        if (c < off) s_ce[c] += s_ce[c + off];
        __syncthreads();
    }
    if (c == 0) out[0] = (float)sqrt(s_ce[0] / (double)NCLS);
}

extern "C" void kernel_launch(void* const* d_in, const int* in_sizes, int n_in,
                              void* d_out, int out_size, void* d_ws, size_t ws_size,
                              hipStream_t stream) {
    const float4* probas = (const float4*)d_in[0];
    const int*    labels = (const int*)d_in[1];

    unsigned int nvec = (unsigned int)(in_sizes[0] / 4);  // 20,000,000

    unsigned int*       g_cnt = (unsigned int*)d_ws;
    unsigned int*       g_acc = (unsigned int*)((char*)d_ws + NSLOTS * 4);
    unsigned long long* g_sum = (unsigned long long*)((char*)d_ws + NSLOTS * 8); // 8B-aligned

    hipMemsetAsync(d_ws, 0, NSLOTS * 16, stream);

    const int threads = 256;
    const int blocks  = 1024;   // 4 blocks/CU, grid-stride, 2 float4 per thread/iter
    mce_accum<<<blocks, threads, 0, stream>>>(probas, labels, g_cnt, g_acc, g_sum, nvec);
    mce_finalize<<<1, 128, 0, stream>>>(g_cnt, g_acc, g_sum, (float*)d_out);
}